// Round 4
// baseline (247.444 us; speedup 1.0000x reference)
//
#include <hip/hip_runtime.h>
#include <hip/hip_cooperative_groups.h>
#include <hip/hip_bf16.h>
#include <math.h>

namespace cg = cooperative_groups;

typedef __attribute__((ext_vector_type(8))) short bf16x8;
typedef __attribute__((ext_vector_type(4))) float f32x4;

__device__ __forceinline__ float leaky(float x) { return x > 0.0f ? x : 0.01f * x; }

__device__ __forceinline__ unsigned short f2b(float f) {
    unsigned u = __builtin_bit_cast(unsigned, f);
    u += 0x7fffu + ((u >> 16) & 1u);
    return (unsigned short)(u >> 16);
}

__device__ __forceinline__ bf16x8 cvt8(float4 u0, float4 u1) {
    bf16x8 r;
    r[0] = (short)f2b(u0.x); r[1] = (short)f2b(u0.y);
    r[2] = (short)f2b(u0.z); r[3] = (short)f2b(u0.w);
    r[4] = (short)f2b(u1.x); r[5] = (short)f2b(u1.y);
    r[6] = (short)f2b(u1.z); r[7] = (short)f2b(u1.w);
    return r;
}

// ---------- stage 1: both HW means -> bf16 (unchanged from R3, validated) ----------
__global__ __launch_bounds__(256) void means_kernel(const float* __restrict__ xm,
                                                    const float* __restrict__ xd,
                                                    unsigned short* __restrict__ xm_b,
                                                    unsigned short* __restrict__ xd_b)
{
    int blk = blockIdx.x;
    int tid = threadIdx.x;
    if (blk < 16384) {
        int lane = tid & 63;
        int wid  = tid >> 6;
        int row  = blk * 4 + wid;
        const float4* r = (const float4*)(xm + (size_t)row * 784);
        float s = 0.0f;
        for (int i = lane; i < 196; i += 64) {
            float4 v = r[i];
            s += v.x + v.y + v.z + v.w;
        }
        #pragma unroll
        for (int off = 32; off; off >>= 1) s += __shfl_xor(s, off);
        if (lane == 0) xm_b[row] = f2b(s * (1.0f / 784.0f));
    } else {
        int b2  = blk - 16384;
        int sub = tid & 15;
        int r   = tid >> 4;
        int row = b2 * 16 + r;
        const float* base = xd + (size_t)row * 49;
        float s = base[sub] + base[sub + 16] + base[sub + 32];
        if (sub == 0) s += base[48];
        #pragma unroll
        for (int off = 8; off; off >>= 1) s += __shfl_xor(s, off);
        if (sub == 0) xd_b[row] = f2b(s * (1.0f / 49.0f));
    }
}

// ---------- mega kernel: all GEMM layers + tail + finalize, cooperative ----------
// grid = 256 blocks x 512 threads (1 block/CU). MFMA 16x16x32 bf16 direct-fragment:
// A lane layout: row=l&15, k-chunk=(l>>4)*8 ; C/D: col=l&15, row=(l>>4)*4+reg  (validated R3)
__global__ __launch_bounds__(512, 2) void mega_kernel(
    char* __restrict__ ws,
    const float* __restrict__ w_shallow,
    const float* __restrict__ ow1, const float* __restrict__ ow2, const float* __restrict__ ow3,
    const float* __restrict__ sw1, const float* __restrict__ sw2, const float* __restrict__ sw3,
    const float* __restrict__ tw1, const float* __restrict__ tw2,
    const float* __restrict__ cw1, const float* __restrict__ cw2,
    const float* __restrict__ qw1, const float* __restrict__ qw2,
    const float* __restrict__ center, const float* __restrict__ proto,
    float* __restrict__ out)
{
    cg::grid_group grid = cg::this_grid();

    const unsigned short* xm_b = (const unsigned short*)(ws);
    const unsigned short* xd_b = (const unsigned short*)(ws + (1 << 20));
    float* P_C  = (float*)(ws + (8 << 20));    // [4][128*2048]
    float* P_D  = (float*)(ws + (16 << 20));   // [2*4][128*1024]
    float* P_E  = (float*)(ws + (32 << 20));   // [2*8][128*512]
    float* ce_t = (float*)(ws + (48 << 20));
    float* osv  = ce_t + 128;
    float* csv  = ce_t + 256;
    float* alv  = ce_t + 384;

    const int tid = threadIdx.x;
    const int bid = blockIdx.x;
    const int w  = tid >> 6;
    const int l  = tid & 63;
    const int lr = l & 15;
    const int lc = l >> 4;
    const int m0 = w * 16;

    __shared__ float o2r[512], s2r[512];
    __shared__ float red[2][64][4];
    __shared__ float o3s[64], s3s[64], t1s[64], c1s[64], q1s[64];
    __shared__ float tmp[4][8];

    // ============ S2: shallow GEMM: [128,512]bf16 @ w_shallow[2048,512]^T, S=4 ============
    {
        const int nt = bid >> 2, s = bid & 3;
        const int n0 = nt * 32;
        const int K = 512, Kc = 128, k0 = s * Kc;
        const unsigned short* Ap = xm_b + (size_t)(m0 + lr) * K + k0 + lc * 8;
        const float* Bp0 = w_shallow + (size_t)(n0 + lr) * K + k0 + lc * 8;
        const float* Bp1 = Bp0 + (size_t)16 * K;
        f32x4 acc0 = {0.f,0.f,0.f,0.f}, acc1 = {0.f,0.f,0.f,0.f};
        for (int kt = 0; kt < Kc; kt += 32) {
            bf16x8 a  = *(const bf16x8*)(Ap + kt);
            bf16x8 b0 = cvt8(*(const float4*)(Bp0 + kt), *(const float4*)(Bp0 + kt + 4));
            bf16x8 b1 = cvt8(*(const float4*)(Bp1 + kt), *(const float4*)(Bp1 + kt + 4));
            acc0 = __builtin_amdgcn_mfma_f32_16x16x32_bf16(a, b0, acc0, 0, 0, 0);
            acc1 = __builtin_amdgcn_mfma_f32_16x16x32_bf16(a, b1, acc1, 0, 0, 0);
        }
        float* Pb = P_C + (size_t)s * (128 * 2048);
        #pragma unroll
        for (int r = 0; r < 4; ++r) {
            int m = m0 + lc * 4 + r;
            Pb[(size_t)m * 2048 + n0 + lr]      = acc0[r];
            Pb[(size_t)m * 2048 + n0 + 16 + lr] = acc1[r];
        }
    }
    grid.sync();

    // ============ S3: layer1 both paths: K=2048 -> N=1024, S=4 ============
    // A0 = xd_b (bf16 direct); A1 = sum of 4 P_C partials (fp32->bf16, no act)
    {
        const int z  = bid >> 7;
        const int r7 = bid & 127;
        const int nt = r7 >> 2, s = r7 & 3;
        const int n0 = nt * 32;
        const int K = 2048, Kc = 512, k0 = s * Kc;
        const float* Bsel = z ? sw1 : ow1;
        const float* Bp0 = Bsel + (size_t)(n0 + lr) * K + k0 + lc * 8;
        const float* Bp1 = Bp0 + (size_t)16 * K;
        const size_t aoff0 = (size_t)(m0 + lr) * K + k0 + lc * 8;
        f32x4 acc0 = {0.f,0.f,0.f,0.f}, acc1 = {0.f,0.f,0.f,0.f};
        for (int kt = 0; kt < Kc; kt += 32) {
            bf16x8 a;
            if (z == 0) {
                a = *(const bf16x8*)(xd_b + aoff0 + kt);
            } else {
                float s0[8] = {0,0,0,0,0,0,0,0};
                #pragma unroll
                for (int p = 0; p < 4; ++p) {
                    const float* q = P_C + (size_t)p * (128 * 2048) + aoff0 + kt;
                    float4 u = *(const float4*)q;
                    float4 v = *(const float4*)(q + 4);
                    s0[0] += u.x; s0[1] += u.y; s0[2] += u.z; s0[3] += u.w;
                    s0[4] += v.x; s0[5] += v.y; s0[6] += v.z; s0[7] += v.w;
                }
                #pragma unroll
                for (int j = 0; j < 8; ++j) a[j] = (short)f2b(s0[j]);
            }
            bf16x8 b0 = cvt8(*(const float4*)(Bp0 + kt), *(const float4*)(Bp0 + kt + 4));
            bf16x8 b1 = cvt8(*(const float4*)(Bp1 + kt), *(const float4*)(Bp1 + kt + 4));
            acc0 = __builtin_amdgcn_mfma_f32_16x16x32_bf16(a, b0, acc0, 0, 0, 0);
            acc1 = __builtin_amdgcn_mfma_f32_16x16x32_bf16(a, b1, acc1, 0, 0, 0);
        }
        float* Pb = P_D + (size_t)(z * 4 + s) * (128 * 1024);
        #pragma unroll
        for (int r = 0; r < 4; ++r) {
            int m = m0 + lc * 4 + r;
            Pb[(size_t)m * 1024 + n0 + lr]      = acc0[r];
            Pb[(size_t)m * 1024 + n0 + 16 + lr] = acc1[r];
        }
    }
    grid.sync();

    // ============ S4: layer2 both paths: K=1024 -> N=512, S=8 ============
    // A = leaky(sum of 4 P_D partials) -> bf16
    {
        const int z  = bid >> 7;
        const int r7 = bid & 127;
        const int nt = r7 >> 3, s = r7 & 7;
        const int n0 = nt * 32;
        const int K = 1024, Kc = 128, k0 = s * Kc;
        const float* Bsel = z ? sw2 : ow2;
        const float* Bp0 = Bsel + (size_t)(n0 + lr) * K + k0 + lc * 8;
        const float* Bp1 = Bp0 + (size_t)16 * K;
        const float* Abase = P_D + (size_t)z * 4 * (128 * 1024);
        const size_t aoff0 = (size_t)(m0 + lr) * K + k0 + lc * 8;
        f32x4 acc0 = {0.f,0.f,0.f,0.f}, acc1 = {0.f,0.f,0.f,0.f};
        for (int kt = 0; kt < Kc; kt += 32) {
            float s0[8] = {0,0,0,0,0,0,0,0};
            #pragma unroll
            for (int p = 0; p < 4; ++p) {
                const float* q = Abase + (size_t)p * (128 * 1024) + aoff0 + kt;
                float4 u = *(const float4*)q;
                float4 v = *(const float4*)(q + 4);
                s0[0] += u.x; s0[1] += u.y; s0[2] += u.z; s0[3] += u.w;
                s0[4] += v.x; s0[5] += v.y; s0[6] += v.z; s0[7] += v.w;
            }
            bf16x8 a;
            #pragma unroll
            for (int j = 0; j < 8; ++j) a[j] = (short)f2b(leaky(s0[j]));
            bf16x8 b0 = cvt8(*(const float4*)(Bp0 + kt), *(const float4*)(Bp0 + kt + 4));
            bf16x8 b1 = cvt8(*(const float4*)(Bp1 + kt), *(const float4*)(Bp1 + kt + 4));
            acc0 = __builtin_amdgcn_mfma_f32_16x16x32_bf16(a, b0, acc0, 0, 0, 0);
            acc1 = __builtin_amdgcn_mfma_f32_16x16x32_bf16(a, b1, acc1, 0, 0, 0);
        }
        float* Pb = P_E + (size_t)(z * 8 + s) * (128 * 512);
        #pragma unroll
        for (int r = 0; r < 4; ++r) {
            int m = m0 + lc * 4 + r;
            Pb[(size_t)m * 512 + n0 + lr]      = acc0[r];
            Pb[(size_t)m * 512 + n0 + 16 + lr] = acc1[r];
        }
    }
    grid.sync();

    // ============ tail: per-sample (blocks 0..127) ============
    if (bid < 128) {
        const int b = bid;
        // reduce P_E partials (8 slices, 2 paths) + leaky
        {
            int e = tid;  // 512 threads, 1 elem each, both paths
            float a0 = 0.f, a1 = 0.f;
            #pragma unroll
            for (int p = 0; p < 8; ++p) {
                a0 += P_E[(size_t)p       * 65536 + b * 512 + e];
                a1 += P_E[(size_t)(8 + p) * 65536 + b * 512 + e];
            }
            o2r[e] = leaky(a0);
            s2r[e] = leaky(a1);
        }
        __syncthreads();
        // layer3 matvecs: p = t>>8, o = (t>>2)&63, q = t&3
        {
            int p = tid >> 8, o = (tid >> 2) & 63, q = tid & 3;
            const float* wr = (p ? sw3 : ow3) + (size_t)o * 512 + q * 128;
            const float* xr = (p ? s2r : o2r) + q * 128;
            float acc = 0.f;
            for (int j = 0; j < 128; ++j) acc += wr[j] * xr[j];
            red[p][o][q] = acc;
        }
        __syncthreads();
        if (tid < 128) {
            int p = tid >> 6, o = tid & 63;
            float v = leaky(red[p][o][0] + red[p][o][1] + red[p][o][2] + red[p][o][3]);
            if (p) s3s[o] = v; else o3s[o] = v;
        }
        __syncthreads();

        float ce_val = 0.f;
        int o = tid;
        if (tid < 64) {
            float acc = 0.f;
            for (int j = 0; j < 64; ++j) acc += tw1[o * 128 + j] * s3s[j];
            for (int j = 0; j < 64; ++j) acc += tw1[o * 128 + 64 + j] * (s3s[j] - center[j]);
            t1s[o] = leaky(acc);
        }
        __syncthreads();
        if (tid < 64) {
            float acc = 0.f;
            for (int j = 0; j < 64; ++j) acc += tw2[o * 64 + j] * t1s[j];
            float tex = leaky(acc);
            float sim[4];
            #pragma unroll
            for (int k = 0; k < 4; ++k) {
                float d = tex - proto[k * 64 + o];
                float v = d * d;
                #pragma unroll
                for (int off = 32; off; off >>= 1) v += __shfl_xor(v, off);
                sim[k] = v;
            }
            int cat = 0; float best = sim[0];
            #pragma unroll
            for (int k = 1; k < 4; ++k) if (sim[k] > best) { best = sim[k]; cat = k; }
            float sume = 0.f;
            #pragma unroll
            for (int k = 0; k < 4; ++k) sume += expf(sim[k] - best);
            ce_val = logf(sume);
            // class layer 1
            acc = 0.f;
            for (int j = 0; j < 64; ++j) acc += cw1[o * 128 + j] * o3s[j];
            for (int j = 0; j < 64; ++j) acc += cw1[o * 128 + 64 + j] * (o3s[j] - proto[cat * 64 + j]);
            c1s[o] = leaky(acc);
            // q layer 1
            acc = 0.f;
            for (int j = 0; j < 64; ++j) acc += qw1[o * 64 + j] * o3s[j];
            q1s[o] = leaky(acc);
        }
        __syncthreads();
        if (tid < 64) {
            float acc = 0.f;
            for (int j = 0; j < 64; ++j) acc += cw2[o * 64 + j] * c1s[j];
            float cf = leaky(acc);
            float dc = cf - center[o];
            float cs = dc * dc;
            #pragma unroll
            for (int off = 32; off; off >>= 1) cs += __shfl_xor(cs, off);
            acc = 0.f;
            for (int j = 0; j < 64; ++j) acc += qw2[o * 64 + j] * q1s[j];
            float qf = leaky(acc);
            float dq = qf - center[o];
            float os = dq * dq;
            #pragma unroll
            for (int off = 32; off; off >>= 1) os += __shfl_xor(os, off);
            if (o == 0) {
                ce_t[b] = ce_val;
                osv[b]  = os;
                csv[b]  = cs;
                alv[b]  = fabsf(os - cs);
            }
        }
    }
    grid.sync();

    // ============ finalize (block 0) ============
    if (bid == 0) {
        float v0 = 0.f, v1 = 0.f, v2 = 0.f, v3 = 0.f;
        if (tid < 128) {
            v0 = ce_t[tid]; v1 = osv[tid]; v2 = csv[tid]; v3 = alv[tid];
        }
        float v[4] = { v0, v1, v2, v3 };
        int lane = tid & 63, wv = tid >> 6;
        #pragma unroll
        for (int i = 0; i < 4; ++i) {
            float x = v[i];
            #pragma unroll
            for (int off = 32; off; off >>= 1) x += __shfl_xor(x, off);
            if (lane == 0) tmp[i][wv] = x;
        }
        __syncthreads();
        if (tid < 4) {
            float s = 0.f;
            #pragma unroll
            for (int j = 0; j < 8; ++j) s += tmp[tid][j];
            out[tid] = s * (1.0f / 128.0f);
        }
    }
}

// ---------- launcher ----------
extern "C" void kernel_launch(void* const* d_in, const int* in_sizes, int n_in,
                              void* d_out, int out_size, void* d_ws, size_t ws_size,
                              hipStream_t stream)
{
    const float* x_mid     = (const float*)d_in[0];
    const float* x_deep    = (const float*)d_in[1];
    const float* w_shallow = (const float*)d_in[2];
    const float* ow1 = (const float*)d_in[3];
    const float* ow2 = (const float*)d_in[4];
    const float* ow3 = (const float*)d_in[5];
    const float* sw1 = (const float*)d_in[6];
    const float* sw2 = (const float*)d_in[7];
    const float* sw3 = (const float*)d_in[8];
    const float* tw1 = (const float*)d_in[9];
    const float* tw2 = (const float*)d_in[10];
    const float* cw1 = (const float*)d_in[11];
    const float* cw2 = (const float*)d_in[12];
    const float* qw1 = (const float*)d_in[13];
    const float* qw2 = (const float*)d_in[14];
    const float* center = (const float*)d_in[15];
    const float* proto  = (const float*)d_in[16];
    float* out = (float*)d_out;

    char* ws = (char*)d_ws;
    unsigned short* xm_b = (unsigned short*)(ws);
    unsigned short* xd_b = (unsigned short*)(ws + (1 << 20));

    means_kernel<<<32768, 256, 0, stream>>>(x_mid, x_deep, xm_b, xd_b);

    void* kargs[] = {
        (void*)&ws, (void*)&w_shallow,
        (void*)&ow1, (void*)&ow2, (void*)&ow3,
        (void*)&sw1, (void*)&sw2, (void*)&sw3,
        (void*)&tw1, (void*)&tw2,
        (void*)&cw1, (void*)&cw2,
        (void*)&qw1, (void*)&qw2,
        (void*)&center, (void*)&proto, (void*)&out
    };
    hipLaunchCooperativeKernel((void*)mega_kernel, dim3(256), dim3(512),
                               kargs, 0, stream);
}

// Round 5
// 247.401 us; speedup vs baseline: 1.0002x; 1.0002x over previous
//
#include <hip/hip_runtime.h>
#include <hip/hip_bf16.h>
#include <math.h>

typedef __attribute__((ext_vector_type(8))) short bf16x8;
typedef __attribute__((ext_vector_type(4))) float f32x4;

__device__ __forceinline__ float leaky(float x) { return x > 0.0f ? x : 0.01f * x; }

__device__ __forceinline__ unsigned short f2b(float f) {
    unsigned u = __builtin_bit_cast(unsigned, f);
    u += 0x7fffu + ((u >> 16) & 1u);
    return (unsigned short)(u >> 16);
}
__device__ __forceinline__ float b2f(unsigned short h) {
    unsigned u = ((unsigned)h) << 16;
    return __builtin_bit_cast(float, u);
}

__device__ __forceinline__ bf16x8 cvt8(float4 u0, float4 u1) {
    bf16x8 r;
    r[0] = (short)f2b(u0.x); r[1] = (short)f2b(u0.y);
    r[2] = (short)f2b(u0.z); r[3] = (short)f2b(u0.w);
    r[4] = (short)f2b(u1.x); r[5] = (short)f2b(u1.y);
    r[6] = (short)f2b(u1.z); r[7] = (short)f2b(u1.w);
    return r;
}

// ---------- stage 1: both HW means -> bf16 ; block 0 also zeroes out[0..3] ----------
__global__ __launch_bounds__(256) void means_kernel(const float* __restrict__ xm,
                                                    const float* __restrict__ xd,
                                                    unsigned short* __restrict__ xm_b,
                                                    unsigned short* __restrict__ xd_b,
                                                    float* __restrict__ out)
{
    int blk = blockIdx.x;
    int tid = threadIdx.x;
    if (blk == 0 && tid < 4) out[tid] = 0.0f;
    if (blk < 16384) {
        int lane = tid & 63;
        int wid  = tid >> 6;
        int row  = blk * 4 + wid;                  // 0..65535
        const float4* r = (const float4*)(xm + (size_t)row * 784);
        float s = 0.0f;
        for (int i = lane; i < 196; i += 64) {
            float4 v = r[i];
            s += v.x + v.y + v.z + v.w;
        }
        #pragma unroll
        for (int off = 32; off; off >>= 1) s += __shfl_xor(s, off);
        if (lane == 0) xm_b[row] = f2b(s * (1.0f / 784.0f));
    } else {
        int b2  = blk - 16384;
        int sub = tid & 15;
        int r   = tid >> 4;
        int row = b2 * 16 + r;                     // 0..262143
        const float* base = xd + (size_t)row * 49;
        float s = base[sub] + base[sub + 16] + base[sub + 32];
        if (sub == 0) s += base[48];
        #pragma unroll
        for (int off = 8; off; off >>= 1) s += __shfl_xor(s, off);
        if (sub == 0) xd_b[row] = f2b(s * (1.0f / 49.0f));
    }
}

// ---------- full-K MFMA GEMM tile: out[128,N] (bf16) = act(A[128,K]bf16 @ B[N,K]^T) ----------
// block = 512 thr = 8 waves; wave w: rows 16w..16w+15, cols n0..n0+31.
// A lane layout: row=l&15, kchunk=(l>>4)*8 ; C/D: col=l&15, row=(l>>4)*4+reg (validated R3)
__device__ __forceinline__ void gemm_block(
    const unsigned short* __restrict__ Ab, const float* __restrict__ Bw,
    unsigned short* __restrict__ Ob, int N, int K, int n0, int act, int tid)
{
    const int w  = tid >> 6;
    const int l  = tid & 63;
    const int lr = l & 15;
    const int lc = l >> 4;
    const int m0 = w * 16;

    const unsigned short* Ap = Ab + (size_t)(m0 + lr) * K + lc * 8;
    const float* Bp0 = Bw + (size_t)(n0 + lr) * K + lc * 8;
    const float* Bp1 = Bp0 + (size_t)16 * K;

    f32x4 acc0 = {0.f,0.f,0.f,0.f}, acc1 = {0.f,0.f,0.f,0.f};
    for (int kt = 0; kt < K; kt += 32) {
        bf16x8 a  = *(const bf16x8*)(Ap + kt);
        bf16x8 b0 = cvt8(*(const float4*)(Bp0 + kt), *(const float4*)(Bp0 + kt + 4));
        bf16x8 b1 = cvt8(*(const float4*)(Bp1 + kt), *(const float4*)(Bp1 + kt + 4));
        acc0 = __builtin_amdgcn_mfma_f32_16x16x32_bf16(a, b0, acc0, 0, 0, 0);
        acc1 = __builtin_amdgcn_mfma_f32_16x16x32_bf16(a, b1, acc1, 0, 0, 0);
    }
    #pragma unroll
    for (int r = 0; r < 4; ++r) {
        int m = m0 + lc * 4 + r;
        float v0 = acc0[r], v1 = acc1[r];
        if (act) { v0 = leaky(v0); v1 = leaky(v1); }
        Ob[(size_t)m * N + n0 + lr]      = f2b(v0);
        Ob[(size_t)m * N + n0 + 16 + lr] = f2b(v1);
    }
}

// g_a: blocks [0,64): shallow_in = xm_b @ w_shallow^T (K=512, N=2048, no act)
//      blocks [64,96): o1 = leaky(xd_b @ ow1^T)       (K=2048, N=1024)
__global__ __launch_bounds__(512) void gemm_a(
    const unsigned short* __restrict__ xm_b, const unsigned short* __restrict__ xd_b,
    const float* __restrict__ w_shallow, const float* __restrict__ ow1,
    unsigned short* __restrict__ sh_b, unsigned short* __restrict__ o1_b)
{
    int bid = blockIdx.x, tid = threadIdx.x;
    if (bid < 64) gemm_block(xm_b, w_shallow, sh_b, 2048, 512,  bid * 32,        0, tid);
    else          gemm_block(xd_b, ow1,       o1_b, 1024, 2048, (bid - 64) * 32, 1, tid);
}

// g_b: blocks [0,32): s1 = leaky(sh_b @ sw1^T) (K=2048, N=1024)
//      blocks [32,48): o2 = leaky(o1_b @ ow2^T) (K=1024, N=512)
__global__ __launch_bounds__(512) void gemm_b(
    const unsigned short* __restrict__ sh_b, const unsigned short* __restrict__ o1_b,
    const float* __restrict__ sw1, const float* __restrict__ ow2,
    unsigned short* __restrict__ s1_b, unsigned short* __restrict__ o2_b)
{
    int bid = blockIdx.x, tid = threadIdx.x;
    if (bid < 32) gemm_block(sh_b, sw1, s1_b, 1024, 2048, bid * 32,        1, tid);
    else          gemm_block(o1_b, ow2, o2_b, 512,  1024, (bid - 32) * 32, 1, tid);
}

// g_c: blocks [0,16): s2 = leaky(s1_b @ sw2^T) (K=1024, N=512)
//      blocks [16,18): o3 = leaky(o2_b @ ow3^T) (K=512, N=64)
__global__ __launch_bounds__(512) void gemm_c(
    const unsigned short* __restrict__ s1_b, const unsigned short* __restrict__ o2_b,
    const float* __restrict__ sw2, const float* __restrict__ ow3,
    unsigned short* __restrict__ s2_b, unsigned short* __restrict__ o3_b)
{
    int bid = blockIdx.x, tid = threadIdx.x;
    if (bid < 16) gemm_block(s1_b, sw2, s2_b, 512, 1024, bid * 32,        1, tid);
    else          gemm_block(o2_b, ow3, o3_b, 64,  512,  (bid - 16) * 32, 1, tid);
}

// ---------- tail: s3 matvec + texture/sim/class/q + atomic accumulate ----------
__global__ __launch_bounds__(256) void tail_kernel(
    const unsigned short* __restrict__ s2_b, const unsigned short* __restrict__ o3_b,
    const float* __restrict__ sw3,
    const float* __restrict__ tw1, const float* __restrict__ tw2,
    const float* __restrict__ cw1, const float* __restrict__ cw2,
    const float* __restrict__ qw1, const float* __restrict__ qw2,
    const float* __restrict__ center, const float* __restrict__ proto,
    float* __restrict__ out)
{
    const int b = blockIdx.x;
    const int t = threadIdx.x;
    __shared__ float s2r[512];
    __shared__ float red[64][4];
    __shared__ float o3s[64], s3s[64], t1s[64], c1s[64], q1s[64];

    for (int e = t; e < 512; e += 256) s2r[e] = b2f(s2_b[b * 512 + e]);
    if (t < 64) o3s[t] = b2f(o3_b[b * 64 + t]);
    __syncthreads();

    // s3 matvec, 4-way K-split: thread t -> out o=(t>>2)&63? use o=t&63, q=t>>6
    {
        int o = t & 63, q = t >> 6;
        const float* wr = sw3 + (size_t)o * 512 + q * 128;
        const float* xr = s2r + q * 128;
        float acc = 0.f;
        for (int j = 0; j < 128; ++j) acc += wr[j] * xr[j];
        red[o][q] = acc;
    }
    __syncthreads();
    if (t < 64) s3s[t] = leaky(red[t][0] + red[t][1] + red[t][2] + red[t][3]);
    __syncthreads();

    float ce_val = 0.f;
    int o = t;
    if (t < 64) {
        float acc = 0.f;
        for (int j = 0; j < 64; ++j) acc += tw1[o * 128 + j] * s3s[j];
        for (int j = 0; j < 64; ++j) acc += tw1[o * 128 + 64 + j] * (s3s[j] - center[j]);
        t1s[o] = leaky(acc);
    }
    __syncthreads();
    if (t < 64) {
        float acc = 0.f;
        for (int j = 0; j < 64; ++j) acc += tw2[o * 64 + j] * t1s[j];
        float tex = leaky(acc);
        float sim[4];
        #pragma unroll
        for (int k = 0; k < 4; ++k) {
            float d = tex - proto[k * 64 + o];
            float v = d * d;
            #pragma unroll
            for (int off = 32; off; off >>= 1) v += __shfl_xor(v, off);
            sim[k] = v;
        }
        int cat = 0; float best = sim[0];
        #pragma unroll
        for (int k = 1; k < 4; ++k) if (sim[k] > best) { best = sim[k]; cat = k; }
        float sume = 0.f;
        #pragma unroll
        for (int k = 0; k < 4; ++k) sume += expf(sim[k] - best);
        ce_val = logf(sume);
        // class layer 1: in = [origin, origin - proto[cat]]
        acc = 0.f;
        for (int j = 0; j < 64; ++j) acc += cw1[o * 128 + j] * o3s[j];
        for (int j = 0; j < 64; ++j) acc += cw1[o * 128 + 64 + j] * (o3s[j] - proto[cat * 64 + j]);
        c1s[o] = leaky(acc);
        // q layer 1
        acc = 0.f;
        for (int j = 0; j < 64; ++j) acc += qw1[o * 64 + j] * o3s[j];
        q1s[o] = leaky(acc);
    }
    __syncthreads();
    if (t < 64) {
        float acc = 0.f;
        for (int j = 0; j < 64; ++j) acc += cw2[o * 64 + j] * c1s[j];
        float cf = leaky(acc);
        float dc = cf - center[o];
        float cs = dc * dc;
        #pragma unroll
        for (int off = 32; off; off >>= 1) cs += __shfl_xor(cs, off);
        acc = 0.f;
        for (int j = 0; j < 64; ++j) acc += qw2[o * 64 + j] * q1s[j];
        float qf = leaky(acc);
        float dq = qf - center[o];
        float os = dq * dq;
        #pragma unroll
        for (int off = 32; off; off >>= 1) os += __shfl_xor(os, off);
        if (o == 0) {
            atomicAdd(out + 0, ce_val * (1.0f / 128.0f));
            atomicAdd(out + 1, os     * (1.0f / 128.0f));
            atomicAdd(out + 2, cs     * (1.0f / 128.0f));
            atomicAdd(out + 3, fabsf(os - cs) * (1.0f / 128.0f));
        }
    }
}

// ---------- launcher ----------
extern "C" void kernel_launch(void* const* d_in, const int* in_sizes, int n_in,
                              void* d_out, int out_size, void* d_ws, size_t ws_size,
                              hipStream_t stream)
{
    const float* x_mid     = (const float*)d_in[0];
    const float* x_deep    = (const float*)d_in[1];
    const float* w_shallow = (const float*)d_in[2];
    const float* ow1 = (const float*)d_in[3];
    const float* ow2 = (const float*)d_in[4];
    const float* ow3 = (const float*)d_in[5];
    const float* sw1 = (const float*)d_in[6];
    const float* sw2 = (const float*)d_in[7];
    const float* sw3 = (const float*)d_in[8];
    const float* tw1 = (const float*)d_in[9];
    const float* tw2 = (const float*)d_in[10];
    const float* cw1 = (const float*)d_in[11];
    const float* cw2 = (const float*)d_in[12];
    const float* qw1 = (const float*)d_in[13];
    const float* qw2 = (const float*)d_in[14];
    const float* center = (const float*)d_in[15];
    const float* proto  = (const float*)d_in[16];
    float* out = (float*)d_out;

    char* ws = (char*)d_ws;
    unsigned short* xm_b = (unsigned short*)(ws);              // 128 KB
    unsigned short* xd_b = (unsigned short*)(ws + (1 << 20));  // 512 KB
    unsigned short* sh_b = (unsigned short*)(ws + (2 << 20));  // 512 KB
    unsigned short* o1_b = (unsigned short*)(ws + (3 << 20));  // 256 KB
    unsigned short* s1_b = (unsigned short*)(ws + (4 << 20));  // 256 KB
    unsigned short* o2_b = (unsigned short*)(ws + (5 << 20));  // 128 KB
    unsigned short* s2_b = (unsigned short*)(ws + (6 << 20));  // 128 KB
    unsigned short* o3_b = (unsigned short*)(ws + (7 << 20));  // 16 KB

    means_kernel<<<32768, 256, 0, stream>>>(x_mid, x_deep, xm_b, xd_b, out);

    gemm_a<<<96, 512, 0, stream>>>(xm_b, xd_b, w_shallow, ow1, sh_b, o1_b);
    gemm_b<<<48, 512, 0, stream>>>(sh_b, o1_b, sw1, ow2, s1_b, o2_b);
    gemm_c<<<18, 512, 0, stream>>>(s1_b, o2_b, sw2, ow3, s2_b, o3_b);

    tail_kernel<<<128, 256, 0, stream>>>(s2_b, o3_b, sw3, tw1, tw2, cw1, cw2,
                                         qw1, qw2, center, proto, out);
}

// Round 6
// 97.857 us; speedup vs baseline: 2.5286x; 2.5282x over previous
//
#include <hip/hip_runtime.h>
#include <hip/hip_bf16.h>
#include <math.h>

typedef __attribute__((ext_vector_type(8))) short bf16x8;
typedef __attribute__((ext_vector_type(4))) float f32x4;

__device__ __forceinline__ float leaky(float x) { return x > 0.0f ? x : 0.01f * x; }

__device__ __forceinline__ unsigned short f2b(float f) {
    unsigned u = __builtin_bit_cast(unsigned, f);
    u += 0x7fffu + ((u >> 16) & 1u);
    return (unsigned short)(u >> 16);
}

__device__ __forceinline__ bf16x8 cvt8(float4 u0, float4 u1) {
    bf16x8 r;
    r[0] = (short)f2b(u0.x); r[1] = (short)f2b(u0.y);
    r[2] = (short)f2b(u0.z); r[3] = (short)f2b(u0.w);
    r[4] = (short)f2b(u1.x); r[5] = (short)f2b(u1.y);
    r[6] = (short)f2b(u1.z); r[7] = (short)f2b(u1.w);
    return r;
}

// ---------- stage 1: both HW means -> bf16 ; blocks >= 32768 zero the C buffers ----------
__global__ __launch_bounds__(256) void means_kernel(const float* __restrict__ xm,
                                                    const float* __restrict__ xd,
                                                    unsigned short* __restrict__ xm_b,
                                                    unsigned short* __restrict__ xd_b,
                                                    float4* __restrict__ zbase)
{
    int blk = blockIdx.x;
    int tid = threadIdx.x;
    if (blk >= 32768) {                            // zero 2.5 MB of atomic-C buffers
        int idx = (blk - 32768) * 256 + tid;       // 640 blocks * 256 = 163840 float4
        zbase[idx] = make_float4(0.f, 0.f, 0.f, 0.f);
        return;
    }
    if (blk < 16384) {
        int lane = tid & 63;
        int wid  = tid >> 6;
        int row  = blk * 4 + wid;                  // 0..65535
        const float4* r = (const float4*)(xm + (size_t)row * 784);
        float s = 0.0f;
        for (int i = lane; i < 196; i += 64) {
            float4 v = r[i];
            s += v.x + v.y + v.z + v.w;
        }
        #pragma unroll
        for (int off = 32; off; off >>= 1) s += __shfl_xor(s, off);
        if (lane == 0) xm_b[row] = f2b(s * (1.0f / 784.0f));
    } else {
        int b2  = blk - 16384;
        int sub = tid & 15;
        int r   = tid >> 4;
        int row = b2 * 16 + r;                     // 0..262143
        const float* base = xd + (size_t)row * 49;
        float s = base[sub] + base[sub + 16] + base[sub + 32];
        if (sub == 0) s += base[48];
        #pragma unroll
        for (int off = 8; off; off >>= 1) s += __shfl_xor(s, off);
        if (sub == 0) xd_b[row] = f2b(s * (1.0f / 49.0f));
    }
}

// ---------- split-K MFMA GEMM, LDS-staged B, atomic fp32 C accumulate ----------
// C[m][n] += sum_{k in slice} actA(A[m][k]) * B[n][k]
// A: bf16 [128,K] or fp32 [128,K] (leaky fused on load if aact)
// grid (N/32, S, paths), block 512 = 8 waves; wave w: rows 16w..16w+15, cols n0..n0+31
// A lane layout: row=l&15, kchunk=(l>>4)*8 ; C/D: col=l&15, row=(l>>4)*4+reg (validated R3)
__global__ __launch_bounds__(512) void gemm_ldsb(
    const void* __restrict__ A0, int a0f, int a0act,
    const void* __restrict__ A1, int a1f, int a1act,
    const float* __restrict__ B0, const float* __restrict__ B1,
    float* __restrict__ C0, float* __restrict__ C1c,
    int N, int K, int S)
{
    __shared__ unsigned short Bs[32][72];          // 64 cols + 8 pad (bank spread)

    const int z = blockIdx.z;
    const void*  A    = z ? A1 : A0;
    const int    af   = z ? a1f : a0f;
    const int    aact = z ? a1act : a0act;
    const float* B    = z ? B1 : B0;
    float*       C    = z ? C1c : C0;

    const int n0 = blockIdx.x * 32;
    const int Kc = K / S;
    const int k0 = blockIdx.y * Kc;

    const int tid = threadIdx.x;
    const int l  = tid & 63;
    const int lr = l & 15;
    const int lc = l >> 4;
    const int m0 = (tid >> 6) * 16;
    const int srow = tid >> 4;                     // 0..31
    const int scol = (tid & 15) * 4;               // 0,4,..,60

    f32x4 acc0 = {0.f,0.f,0.f,0.f}, acc1 = {0.f,0.f,0.f,0.f};

    for (int kt = 0; kt < Kc; kt += 64) {
        // coalesced global load of B tile 32x64 fp32
        float4 v = *(const float4*)(B + (size_t)(n0 + srow) * K + k0 + kt + scol);
        __syncthreads();                           // prev-iter Bs reads done
        Bs[srow][scol + 0] = f2b(v.x);
        Bs[srow][scol + 1] = f2b(v.y);
        Bs[srow][scol + 2] = f2b(v.z);
        Bs[srow][scol + 3] = f2b(v.w);
        __syncthreads();

        #pragma unroll
        for (int kc = 0; kc < 2; ++kc) {
            size_t aoff = (size_t)(m0 + lr) * K + k0 + kt + kc * 32 + lc * 8;
            bf16x8 a;
            if (!af) {
                a = *(const bf16x8*)((const unsigned short*)A + aoff);
            } else {
                const float* p = (const float*)A + aoff;
                float4 u0 = *(const float4*)p;
                float4 u1 = *(const float4*)(p + 4);
                if (aact) {
                    u0.x = leaky(u0.x); u0.y = leaky(u0.y);
                    u0.z = leaky(u0.z); u0.w = leaky(u0.w);
                    u1.x = leaky(u1.x); u1.y = leaky(u1.y);
                    u1.z = leaky(u1.z); u1.w = leaky(u1.w);
                }
                a = cvt8(u0, u1);
            }
            bf16x8 b0 = *(const bf16x8*)&Bs[lr][kc * 32 + lc * 8];
            bf16x8 b1 = *(const bf16x8*)&Bs[16 + lr][kc * 32 + lc * 8];
            acc0 = __builtin_amdgcn_mfma_f32_16x16x32_bf16(a, b0, acc0, 0, 0, 0);
            acc1 = __builtin_amdgcn_mfma_f32_16x16x32_bf16(a, b1, acc1, 0, 0, 0);
        }
    }

    // scattered fp32 atomic accumulate (S-way per element, spread over MB)
    #pragma unroll
    for (int r = 0; r < 4; ++r) {
        int m = m0 + lc * 4 + r;
        atomicAdd(&C[(size_t)m * N + n0 + lr],      acc0[r]);
        atomicAdd(&C[(size_t)m * N + n0 + 16 + lr], acc1[r]);
    }
}

// ---------- tail: layer-2 act + both layer-3 matvecs + texture/sim/class/q ----------
// one block (256 threads) per sample; C3o/C3s are fp32 pre-activation of layer 2
__global__ __launch_bounds__(256) void tail_kernel(
    const float* __restrict__ C3o, const float* __restrict__ C3s,
    const float* __restrict__ ow3, const float* __restrict__ sw3,
    const float* __restrict__ tw1, const float* __restrict__ tw2,
    const float* __restrict__ cw1, const float* __restrict__ cw2,
    const float* __restrict__ qw1, const float* __restrict__ qw2,
    const float* __restrict__ center, const float* __restrict__ proto,
    float* __restrict__ ce_t, float* __restrict__ osv,
    float* __restrict__ csv, float* __restrict__ alv)
{
    const int b = blockIdx.x;
    const int t = threadIdx.x;
    __shared__ float o2r[512], s2r[512];
    __shared__ float red[2][64][4];
    __shared__ float o3s[64], s3s[64], t1s[64], c1s[64], q1s[64];

    for (int e = t; e < 512; e += 256) {
        o2r[e] = leaky(C3o[b * 512 + e]);
        s2r[e] = leaky(C3s[b * 512 + e]);
    }
    __syncthreads();

    // layer-3 matvecs (both paths), 4-way K-split per output
    {
        int o = t & 63, q = t >> 6;
        const float* wro = ow3 + (size_t)o * 512 + q * 128;
        const float* wrs = sw3 + (size_t)o * 512 + q * 128;
        const float* xo = o2r + q * 128;
        const float* xs = s2r + q * 128;
        float ao = 0.f, as_ = 0.f;
        for (int j = 0; j < 128; ++j) {
            ao  += wro[j] * xo[j];
            as_ += wrs[j] * xs[j];
        }
        red[0][o][q] = ao;
        red[1][o][q] = as_;
    }
    __syncthreads();
    if (t < 64) {
        o3s[t] = leaky(red[0][t][0] + red[0][t][1] + red[0][t][2] + red[0][t][3]);
        s3s[t] = leaky(red[1][t][0] + red[1][t][1] + red[1][t][2] + red[1][t][3]);
    }
    __syncthreads();

    float ce_val = 0.f;
    int o = t;
    if (t < 64) {
        float acc = 0.f;
        for (int j = 0; j < 64; ++j) acc += tw1[o * 128 + j] * s3s[j];
        for (int j = 0; j < 64; ++j) acc += tw1[o * 128 + 64 + j] * (s3s[j] - center[j]);
        t1s[o] = leaky(acc);
    }
    __syncthreads();
    if (t < 64) {
        float acc = 0.f;
        for (int j = 0; j < 64; ++j) acc += tw2[o * 64 + j] * t1s[j];
        float tex = leaky(acc);
        float sim[4];
        #pragma unroll
        for (int k = 0; k < 4; ++k) {
            float d = tex - proto[k * 64 + o];
            float v = d * d;
            #pragma unroll
            for (int off = 32; off; off >>= 1) v += __shfl_xor(v, off);
            sim[k] = v;
        }
        int cat = 0; float best = sim[0];
        #pragma unroll
        for (int k = 1; k < 4; ++k) if (sim[k] > best) { best = sim[k]; cat = k; }
        float sume = 0.f;
        #pragma unroll
        for (int k = 0; k < 4; ++k) sume += expf(sim[k] - best);
        ce_val = logf(sume);
        // class layer 1: in = [origin, origin - proto[cat]]
        acc = 0.f;
        for (int j = 0; j < 64; ++j) acc += cw1[o * 128 + j] * o3s[j];
        for (int j = 0; j < 64; ++j) acc += cw1[o * 128 + 64 + j] * (o3s[j] - proto[cat * 64 + j]);
        c1s[o] = leaky(acc);
        // q layer 1
        acc = 0.f;
        for (int j = 0; j < 64; ++j) acc += qw1[o * 64 + j] * o3s[j];
        q1s[o] = leaky(acc);
    }
    __syncthreads();
    if (t < 64) {
        float acc = 0.f;
        for (int j = 0; j < 64; ++j) acc += cw2[o * 64 + j] * c1s[j];
        float cf = leaky(acc);
        float dc = cf - center[o];
        float cs = dc * dc;
        #pragma unroll
        for (int off = 32; off; off >>= 1) cs += __shfl_xor(cs, off);
        acc = 0.f;
        for (int j = 0; j < 64; ++j) acc += qw2[o * 64 + j] * q1s[j];
        float qf = leaky(acc);
        float dq = qf - center[o];
        float os = dq * dq;
        #pragma unroll
        for (int off = 32; off; off >>= 1) os += __shfl_xor(os, off);
        if (o == 0) {
            ce_t[b] = ce_val;
            osv[b]  = os;
            csv[b]  = cs;
            alv[b]  = fabsf(os - cs);
        }
    }
}

// ---------- finalize ----------
__global__ __launch_bounds__(128) void finalize_kernel(
    const float* __restrict__ ce_t, const float* __restrict__ osv,
    const float* __restrict__ csv, const float* __restrict__ alv,
    float* __restrict__ out)
{
    int t = threadIdx.x;
    float v[4] = { ce_t[t], osv[t], csv[t], alv[t] };
    __shared__ float tmp[4][2];
    int lane = t & 63, w = t >> 6;
    #pragma unroll
    for (int i = 0; i < 4; ++i) {
        float x = v[i];
        #pragma unroll
        for (int off = 32; off; off >>= 1) x += __shfl_xor(x, off);
        if (lane == 0) tmp[i][w] = x;
    }
    __syncthreads();
    if (t < 4) out[t] = (tmp[t][0] + tmp[t][1]) * (1.0f / 128.0f);
}

// ---------- launcher ----------
extern "C" void kernel_launch(void* const* d_in, const int* in_sizes, int n_in,
                              void* d_out, int out_size, void* d_ws, size_t ws_size,
                              hipStream_t stream)
{
    const float* x_mid     = (const float*)d_in[0];
    const float* x_deep    = (const float*)d_in[1];
    const float* w_shallow = (const float*)d_in[2];
    const float* ow1 = (const float*)d_in[3];
    const float* ow2 = (const float*)d_in[4];
    const float* ow3 = (const float*)d_in[5];
    const float* sw1 = (const float*)d_in[6];
    const float* sw2 = (const float*)d_in[7];
    const float* sw3 = (const float*)d_in[8];
    const float* tw1 = (const float*)d_in[9];
    const float* tw2 = (const float*)d_in[10];
    const float* cw1 = (const float*)d_in[11];
    const float* cw2 = (const float*)d_in[12];
    const float* qw1 = (const float*)d_in[13];
    const float* qw2 = (const float*)d_in[14];
    const float* center = (const float*)d_in[15];
    const float* proto  = (const float*)d_in[16];
    float* out = (float*)d_out;

    float* wf = (float*)d_ws;
    // contiguous zeroed region: 655360 floats = 2.5 MB
    float* C1  = wf;                   // [128,2048] = 262144
    float* C2o = wf + 262144;          // [128,1024] = 131072
    float* C2s = wf + 393216;          // [128,1024]
    float* C3o = wf + 524288;          // [128,512]  = 65536
    float* C3s = wf + 589824;          // [128,512]
    // bf16 buffers after the zeroed region
    unsigned short* xm_b = (unsigned short*)(wf + 655360);            // [128,512]
    unsigned short* xd_b = (unsigned short*)((char*)xm_b + 131072);   // [128,2048]
    float* ce_t = (float*)((char*)xm_b + 131072 + 524288);
    float* osv  = ce_t + 128;
    float* csv  = ce_t + 256;
    float* alv  = ce_t + 384;

    // 1: means + C-zeroing (640 extra blocks)
    means_kernel<<<33408, 256, 0, stream>>>(x_mid, x_deep, xm_b, xd_b, (float4*)wf);

    // 2: G1 shallow: C1 = xm_b @ w_shallow^T   (N=2048, K=512, S=4 -> 256 blocks)
    gemm_ldsb<<<dim3(64, 4, 1), 512, 0, stream>>>(
        xm_b, 0, 0, xm_b, 0, 0, w_shallow, w_shallow, C1, C1, 2048, 512, 4);

    // 3: G2 layer1 pair: C2o = xd_b @ ow1^T ; C2s = C1 @ sw1^T  (N=1024, K=2048, S=8 -> 512 blocks)
    gemm_ldsb<<<dim3(32, 8, 2), 512, 0, stream>>>(
        xd_b, 0, 0, C1, 1, 0, ow1, sw1, C2o, C2s, 1024, 2048, 8);

    // 4: G3 layer2 pair: C3o = leaky(C2o) @ ow2^T ; C3s = leaky(C2s) @ sw2^T  (N=512, K=1024, S=8 -> 256 blocks)
    gemm_ldsb<<<dim3(16, 8, 2), 512, 0, stream>>>(
        C2o, 1, 1, C2s, 1, 1, ow2, sw2, C3o, C3s, 512, 1024, 8);

    // 5: tail
    tail_kernel<<<128, 256, 0, stream>>>(C3o, C3s, ow3, sw3, tw1, tw2, cw1, cw2,
                                         qw1, qw2, center, proto, ce_t, osv, csv, alv);

    // 6: finalize
    finalize_kernel<<<1, 128, 0, stream>>>(ce_t, osv, csv, alv, out);
}